// Round 4
// baseline (287.456 us; speedup 1.0000x reference)
//
#include <hip/hip_runtime.h>
#include <math.h>

#define NSWEEP_FULL 6   // full sweeps (intra+cross); followed by one final intra phase
#define NCHUNK 16       // n-chunks in max_outer (2048/16 = 128 rows per block)

typedef float v2f __attribute__((ext_vector_type(2)));
typedef unsigned u2v __attribute__((ext_vector_type(2)));

__device__ __forceinline__ float dot4f(const float4 a, const float4 b) {
    return a.x * b.x + a.y * b.y + a.z * b.z + a.w * b.w;
}
// monotone float<->uint map so unsigned atomicMax == float max (handles negatives)
__device__ __forceinline__ unsigned mapf(float v) {
    unsigned u = __float_as_uint(v);
    return (u & 0x80000000u) ? ~u : (u | 0x80000000u);
}
__device__ __forceinline__ float unmapf(unsigned u) {
    return __uint_as_float((u & 0x80000000u) ? (u ^ 0x80000000u) : ~u);
}

// Cross-half (lane ^ 32) sum. Symmetric permlane32_swap form: with both
// operands = part, each lane's output pair is {part[i], part[i^32]}, so
// r.x + r.y == part + shfl_xor(part,32) BIT-EXACTLY (fp add commutes).
__device__ __forceinline__ float xor32_sum(float part) {
#if __has_builtin(__builtin_amdgcn_permlane32_swap)
    const u2v r = __builtin_amdgcn_permlane32_swap(__float_as_uint(part),
                                                   __float_as_uint(part),
                                                   false, false);
    return __uint_as_float(r.x) + __uint_as_float(r.y);
#else
    return part + __shfl_xor(part, 32);
#endif
}

// ws[0..65535] <- map(-inf)   (atomic-fallback path only)
__global__ __launch_bounds__(256) void init_ws(unsigned* __restrict__ wsu) {
    wsu[blockIdx.x * 256 + threadIdx.x] = 0x007FFFFFu;  // map of 0xFF800000 (-inf)
}

// Shared compute core for both max_outer variants: per-block 4x4-tile max.
// Products packed (v_pk_mul_f32); max stays scalar (no pk fp32 max on CDNA).
__device__ __forceinline__ void max_outer_core(const float* __restrict__ x,
                                               float m[4][4], float* xs,
                                               int b, int n0, int t, int ti, int tj) {
    v2f m2[4][2];
#pragma unroll
    for (int a = 0; a < 4; ++a)
#pragma unroll
        for (int c = 0; c < 2; ++c) m2[a][c] = (v2f){-3.402823466e38f, -3.402823466e38f};

    const int row = t >> 3, col8 = t & 7;     // staging map: 32 rows x 8 float-octs
    for (int sub = 0; sub < (2048 / NCHUNK) / 32; ++sub) {
        const float4* src4 =
            (const float4*)(x + (size_t)(b * 2048 + n0 + sub * 32 + row) * 64) + col8 * 2;
        float4* dst4 = (float4*)(xs + row * 64) + col8 * 2;
        dst4[0] = src4[0];
        dst4[1] = src4[1];
        __syncthreads();
#pragma unroll 8
        for (int rr = 0; rr < 32; ++rr) {
            const float4 av = ((const float4*)(xs + rr * 64))[ti];  // broadcast read
            const float4 bv = ((const float4*)(xs + rr * 64))[tj];  // stride-1 read
            const v2f b01 = {bv.x, bv.y}, b23 = {bv.z, bv.w};
            const float aa[4] = {av.x, av.y, av.z, av.w};
#pragma unroll
            for (int a = 0; a < 4; ++a) {
                const v2f av2 = {aa[a], aa[a]};
                const v2f p01 = av2 * b01;   // v_pk_mul_f32
                const v2f p23 = av2 * b23;
                m2[a][0].x = fmaxf(m2[a][0].x, p01.x);
                m2[a][0].y = fmaxf(m2[a][0].y, p01.y);
                m2[a][1].x = fmaxf(m2[a][1].x, p23.x);
                m2[a][1].y = fmaxf(m2[a][1].y, p23.y);
            }
        }
        __syncthreads();
    }
#pragma unroll
    for (int a = 0; a < 4; ++a) {
        m[a][0] = m2[a][0].x; m[a][1] = m2[a][0].y;
        m[a][2] = m2[a][1].x; m[a][3] = m2[a][1].y;
    }
}

// No-atomic path: each (chunk,b) block writes its private 64x64 max partial.
// ws layout: wsp[(b*NCHUNK + chunk)*4096 + i*64 + j]. grid = (NCHUNK, 16).
__global__ __launch_bounds__(256) void max_outer_part(const float* __restrict__ x,
                                                      float* __restrict__ wsp) {
    __shared__ __align__(16) float xs[32 * 64];
    const int b = blockIdx.y;
    const int t = threadIdx.x;
    const int ti = t >> 4, tj = t & 15;
    float m[4][4];
    max_outer_core(x, m, xs, b, blockIdx.x * (2048 / NCHUNK), t, ti, tj);
    float* cell = wsp + (((size_t)b * NCHUNK + blockIdx.x) << 12);
#pragma unroll
    for (int a = 0; a < 4; ++a) {
        float4 v;
        v.x = m[a][0]; v.y = m[a][1]; v.z = m[a][2]; v.w = m[a][3];
        *(float4*)(cell + (ti * 4 + a) * 64 + tj * 4) = v;
    }
}

// Atomic fallback (used only if ws too small): upper triangle only.
__global__ __launch_bounds__(256) void max_outer_atomic(const float* __restrict__ x,
                                                        unsigned* __restrict__ wsu) {
    __shared__ __align__(16) float xs[32 * 64];
    const int b = blockIdx.y;
    const int t = threadIdx.x;
    const int ti = t >> 4, tj = t & 15;
    float m[4][4];
    max_outer_core(x, m, xs, b, blockIdx.x * (2048 / NCHUNK), t, ti, tj);
    unsigned* cell = wsu + b * 4096;
#pragma unroll
    for (int a = 0; a < 4; ++a)
#pragma unroll
        for (int c = 0; c < 4; ++c) {
            const int gi = ti * 4 + a, gj = tj * 4 + c;
            if (gj >= gi) atomicMax(cell + gi * 64 + gj, mapf(m[a][c]));
        }
}

// Packed 32-dot: 16 v_pk_fma_f32 instead of 32 v_fma_f32.
__device__ __forceinline__ float dot32v(const v2f* w, const v2f* p) {
    v2f a0 = {0.f, 0.f}, a1 = a0, a2 = a0, a3 = a0;
#pragma unroll
    for (int i = 0; i < 16; i += 4) {
        a0 = __builtin_elementwise_fma(w[i + 0], p[i + 0], a0);
        a1 = __builtin_elementwise_fma(w[i + 1], p[i + 1], a1);
        a2 = __builtin_elementwise_fma(w[i + 2], p[i + 2], a2);
        a3 = __builtin_elementwise_fma(w[i + 3], p[i + 3], a3);
    }
    const v2f s = (a0 + a1) + (a2 + a3);
    return s.x + s.y;
}

// Rotation + packed update (32 pk-mul+pk-fma pairs instead of 64 scalar).
__device__ __forceinline__ void rot_update(float g, float np, bool lo, float& n,
                                           v2f* w, const v2f* p) {
    float cc = 1.f, ss2 = 0.f, dn = 0.f;
    if (fabsf(g) > 1e-25f) {
        const float a2 = lo ? n : np;   // norm^2 of lower-indexed column
        const float b2 = lo ? np : n;
        const float tau = (b2 - a2) * 0.5f * __builtin_amdgcn_rcpf(g);
        const float t = (tau >= 0.f ? 1.f : -1.f) *
                        __builtin_amdgcn_rcpf(fabsf(tau) + sqrtf(fmaf(tau, tau, 1.f)));
        cc = __builtin_amdgcn_rsqf(fmaf(t, t, 1.f));
        const float s = t * cc;
        const float sg = lo ? -1.f : 1.f;
        ss2 = sg * s;          // lo: w' = c w - s p ; hi: w' = c w + s p
        dn = sg * (t * g);     // a2' = a2 - t g ; b2' = b2 + t g
    }
    n += dn;
    const v2f ccv = {cc, cc}, ssv = {ss2, ss2};
#pragma unroll
    for (int i = 0; i < 16; ++i)
        w[i] = __builtin_elementwise_fma(ssv, p[i], w[i] * ccv);
}

// Column exchange helpers (xbuf row = 36 floats: 32 data + norm + pad).
__device__ __forceinline__ void store_col(float* myx, const v2f* w, float n) {
#pragma unroll
    for (int c = 0; c < 8; ++c) {
        float4 v;
        v.x = w[2 * c].x; v.y = w[2 * c].y;
        v.z = w[2 * c + 1].x; v.w = w[2 * c + 1].y;
        ((float4*)myx)[c] = v;
    }
    myx[32] = n;
}
__device__ __forceinline__ void load_col(const float* ox, v2f* p, float& np) {
#pragma unroll
    for (int c = 0; c < 8; ++c) {
        const float4 v = ((const float4*)ox)[c];
        p[2 * c] = (v2f){v.x, v.y};
        p[2 * c + 1] = (v2f){v.z, v.w};
    }
    np = ox[32];
}

// One-sided Jacobi, 2 waves per batch, TWO ROUNDS PER EXCHANGE (lookahead).
// Wave W owns COLUMNS W*32..W*32+31; each column split across lanes l / l+32.
// Rounds are fused in pairs (m, m+1): one LDS publish + 3 partner reads
// (cols c^m, c^(m+1), c^(m^(m+1))) serve both rounds. Round m's rotation of
// the pair (c^(m+1), c^(m^(m+1))) is REPLICATED locally — same inputs, same
// fp ops as its owner computes -> bit-identical registers everywhere, so
// the 409-round trajectory (and absmax) is unchanged while the serial
// store->load LDS round-trips drop 409 -> 208 and barriers 192 -> 96.
// Intra blocks (m<32): single-buffer, in-wave lockstep + compiler fence.
// Cross blocks (m>=32): double-buffered, ONE barrier per 2 rounds.
// 6 full sweeps + final intra phase = 409 rounds (fp32 floor; 378 fails).
// grid = 16, block = 128.
__global__ __launch_bounds__(128) void jacobi_sqrt(const void* __restrict__ wsv,
                                                   float* __restrict__ out,
                                                   int nchunk, int mapped) {
    __shared__ __align__(16) float Mlds[64 * 68];      // original M rows (stride 68)
    __shared__ __align__(16) float Ulds[64 * 68];      // U rows
    __shared__ __align__(16) float gl[64];             // signed sqrt eigenvalues
    __shared__ __align__(16) float xbuf[2][2][64][36]; // [buf][wave][lane][32w+n+pad]
    __shared__ float gred[2][2][64];                   // epilogue reductions
    const int b = blockIdx.x;
    const int tid = threadIdx.x;
    const int wave = tid >> 6;
    const int lane = tid & 63;
    const int col = wave * 32 + (lane & 31);  // column this lane serves
    const int r0 = (lane >> 5) * 32;          // first row of the half it holds

    v2f w[16], p1[16], p2[16], p3[16];
    // load my half-column + stash M rows in LDS for the epilogue
    if (mapped) {
        const unsigned* wsu = (const unsigned*)wsv;
#pragma unroll
        for (int i = 0; i < 16; ++i) {
            float vv[2];
#pragma unroll
            for (int h = 0; h < 2; ++h) {
                const int row = r0 + 2 * i + h;
                const int rr = row < col ? row : col;
                const int cc = row < col ? col : row;
                vv[h] = unmapf(wsu[b * 4096 + rr * 64 + cc]);
                Mlds[row * 68 + col] = vv[h];
            }
            w[i] = (v2f){vv[0], vv[1]};
        }
    } else {
        const float* wsp = (const float*)wsv + (((size_t)b * nchunk) << 12);
#pragma unroll
        for (int i = 0; i < 16; ++i) w[i] = (v2f){-3.402823466e38f, -3.402823466e38f};
#pragma unroll 1
        for (int ch = 0; ch < nchunk; ++ch) {
            const float* base = wsp + ((size_t)ch << 12) + (size_t)r0 * 64 + col;
#pragma unroll
            for (int i = 0; i < 16; ++i) {
                w[i].x = fmaxf(w[i].x, base[(2 * i) * 64]);
                w[i].y = fmaxf(w[i].y, base[(2 * i + 1) * 64]);
            }
        }
#pragma unroll
        for (int i = 0; i < 16; ++i) {
            Mlds[(r0 + 2 * i) * 68 + col] = w[i].x;
            Mlds[(r0 + 2 * i + 1) * 68 + col] = w[i].y;
        }
    }
    // initial column norm^2 (maintained analytically through the rotations)
    float n;
    {
        const float part = dot32v(w, w);
        n = xor32_sum(part);
    }

#pragma unroll 1
    for (int sweep = 0; sweep < NSWEEP_FULL + 1; ++sweep) {
        // ---- intra-wave: 15 fused double-rounds + 1 single, no barriers ----
#pragma unroll 1
        for (int m = 1; m < 31; m += 2) {
            const int m2 = m + 1, m3 = m ^ m2;
            store_col(&xbuf[0][wave][lane][0], w, n);
            asm volatile("" ::: "memory");
            float np1, np2, np3;
            load_col(&xbuf[0][wave][lane ^ m][0], p1, np1);
            load_col(&xbuf[0][wave][lane ^ m2][0], p2, np2);
            load_col(&xbuf[0][wave][lane ^ m3][0], p3, np3);
            const int c5 = lane & 31;
            // round m, my pair (col, col^m)
            {
                const float g = xor32_sum(dot32v(w, p1));
                rot_update(g, np1, c5 < (c5 ^ m), n, w, p1);
            }
            // round m, replicated partner pair (col^m2, col^m3): bit-identical
            // to its owner's computation (same inputs, same formula)
            {
                const float g = xor32_sum(dot32v(p2, p3));
                rot_update(g, np3, (c5 ^ m2) < (c5 ^ m3), np2, p2, p3);
            }
            // round m2, my pair (col, col^m2) against locally-updated p2
            {
                const float g = xor32_sum(dot32v(w, p2));
                rot_update(g, np2, c5 < (c5 ^ m2), n, w, p2);
            }
        }
        {   // leftover single round m=31
            store_col(&xbuf[0][wave][lane][0], w, n);
            asm volatile("" ::: "memory");
            float np1;
            load_col(&xbuf[0][wave][lane ^ 31][0], p1, np1);
            const float g = xor32_sum(dot32v(w, p1));
            rot_update(g, np1, (lane & 31) < ((lane & 31) ^ 31), n, w, p1);
        }
        if (sweep == NSWEEP_FULL) break;  // final phase is intra-only
        // ---- cross-wave: 16 fused double-rounds, ONE barrier each ----
#pragma unroll 1
        for (int m = 32; m < 64; m += 2) {
            const int m2 = m + 1;              // m ^ m2 == 1 (replica partner intra)
            const int buf = (m >> 1) & 1;
            store_col(&xbuf[buf][wave][lane][0], w, n);
            __syncthreads();
            float np1, np2, np3;
            load_col(&xbuf[buf][wave ^ 1][lane ^ (m & 31)][0], p1, np1);
            load_col(&xbuf[buf][wave ^ 1][lane ^ (m2 & 31)][0], p2, np2);
            load_col(&xbuf[buf][wave][lane ^ 1][0], p3, np3);
            // round m, my pair (col, col^m): lower column lives in wave 0
            {
                const float g = xor32_sum(dot32v(w, p1));
                rot_update(g, np1, wave == 0, n, w, p1);
            }
            // round m, replicated pair (col^m2 [other wave], col^1 [my wave]):
            // lower column of that pair lives in wave^1 -> lo iff wave==1
            {
                const float g = xor32_sum(dot32v(p2, p3));
                rot_update(g, np3, wave != 0, np2, p2, p3);
            }
            // round m2, my pair (col, col^m2)
            {
                const float g = xor32_sum(dot32v(w, p2));
                rot_update(g, np2, wave == 0, n, w, p2);
            }
        }
    }

    // ---- exact norm -> u (intra-wave) ----
    {
        const float part = dot32v(w, w);
        const float nrm = xor32_sum(part);
        const float inv = rsqrtf(fmaxf(nrm, 1e-30f));
        const v2f iv = {inv, inv};
#pragma unroll
        for (int i = 0; i < 16; ++i) w[i] = w[i] * iv;
    }
    // U rows into LDS (conflict-free: distinct cols mod 32 per half)
#pragma unroll
    for (int i = 0; i < 16; ++i) {
        Ulds[(r0 + 2 * i) * 68 + col] = w[i].x;
        Ulds[(r0 + 2 * i + 1) * 68 + col] = w[i].y;
    }
    __syncthreads();

    // ---- switch to row-split layout: lane = column, wave owns rows ----
    const int rbase = wave * 32;
    const int obase = 32 - rbase;
    float w2[32], p2r[32];
#pragma unroll
    for (int i = 0; i < 32; ++i) w2[i] = Ulds[(rbase + i) * 68 + lane];
#pragma unroll
    for (int i = 0; i < 32; ++i) p2r[i] = Ulds[(obase + i) * 68 + lane];

    // ---- signed eigenvalue: rho = u^T M u (i split by ownership, j full) ----
    {
        float rho = 0.f;
#pragma unroll 1
        for (int ii = 0; ii < 32; ++ii) {
            const int i = rbase + ii;
            const float4* mrw = (const float4*)(Mlds + i * 68) + (rbase >> 2);  // rows of w2
            const float4* mrp = (const float4*)(Mlds + i * 68) + (obase >> 2);  // rows of p2r
            float z0 = 0, z1 = 0, z2 = 0, z3 = 0;
#pragma unroll
            for (int c = 0; c < 8; c += 4) {
                float4 mv;
                mv = mrw[c + 0]; z0 += mv.x * w2[4 * c + 0]  + mv.y * w2[4 * c + 1]  + mv.z * w2[4 * c + 2]  + mv.w * w2[4 * c + 3];
                mv = mrw[c + 1]; z1 += mv.x * w2[4 * c + 4]  + mv.y * w2[4 * c + 5]  + mv.z * w2[4 * c + 6]  + mv.w * w2[4 * c + 7];
                mv = mrw[c + 2]; z2 += mv.x * w2[4 * c + 8]  + mv.y * w2[4 * c + 9]  + mv.z * w2[4 * c + 10] + mv.w * w2[4 * c + 11];
                mv = mrw[c + 3]; z3 += mv.x * w2[4 * c + 12] + mv.y * w2[4 * c + 13] + mv.z * w2[4 * c + 14] + mv.w * w2[4 * c + 15];
                mv = mrp[c + 0]; z0 += mv.x * p2r[4 * c + 0]  + mv.y * p2r[4 * c + 1]  + mv.z * p2r[4 * c + 2]  + mv.w * p2r[4 * c + 3];
                mv = mrp[c + 1]; z1 += mv.x * p2r[4 * c + 4]  + mv.y * p2r[4 * c + 5]  + mv.z * p2r[4 * c + 6]  + mv.w * p2r[4 * c + 7];
                mv = mrp[c + 2]; z2 += mv.x * p2r[4 * c + 8]  + mv.y * p2r[4 * c + 9]  + mv.z * p2r[4 * c + 10] + mv.w * p2r[4 * c + 11];
                mv = mrp[c + 3]; z3 += mv.x * p2r[4 * c + 12] + mv.y * p2r[4 * c + 13] + mv.z * p2r[4 * c + 14] + mv.w * p2r[4 * c + 15];
            }
            rho = fmaf(w2[ii], (z0 + z1) + (z2 + z3), rho);
        }
        gred[1][wave][lane] = rho;
        __syncthreads();
        const float rs = gred[1][0][lane] + gred[1][1][lane];
        gl[lane] = (rs >= 0.f) ? sqrtf(rs) : -sqrtf(-rs);  // both waves write same value
    }
    __syncthreads();

    // ---- F[i][lane] = sum_k g_k U[i][k] U[lane][k], i over my rows ----
    {
        float4 rr[16];  // row `lane` of U scaled by g
#pragma unroll
        for (int c = 0; c < 16; ++c) {
            const float4 uv = ((const float4*)(Ulds + lane * 68))[c];
            const float4 gv = ((const float4*)gl)[c];  // broadcast
            rr[c].x = uv.x * gv.x; rr[c].y = uv.y * gv.y;
            rr[c].z = uv.z * gv.z; rr[c].w = uv.w * gv.w;
        }
        float sq = 0.f;
#pragma unroll 1
        for (int ii = 0; ii < 32; ++ii) {
            const int i = rbase + ii;
            const float4* ur = (const float4*)(Ulds + i * 68);  // broadcast
            float f0 = 0, f1 = 0, f2 = 0, f3 = 0;
#pragma unroll
            for (int c = 0; c < 16; c += 4) {
                f0 += dot4f(ur[c + 0], rr[c + 0]);
                f1 += dot4f(ur[c + 1], rr[c + 1]);
                f2 += dot4f(ur[c + 2], rr[c + 2]);
                f3 += dot4f(ur[c + 3], rr[c + 3]);
            }
            const float fv = (f0 + f1) + (f2 + f3);
            sq = fmaf(fv, fv, sq);
            Mlds[i * 68 + lane] = fv;  // M is dead; reuse as F staging
        }
#pragma unroll
        for (int d = 1; d < 64; d <<= 1) sq += __shfl_xor(sq, d);
        gred[0][wave][lane] = sq;
        __syncthreads();
        const float tot = gred[0][0][lane] + gred[0][1][lane];
        const float scale = 1.f / fmaxf(sqrtf(tot), 1e-12f);
#pragma unroll 1
        for (int ii = 0; ii < 32; ++ii)
            out[(size_t)b * 4096 + (rbase + ii) * 64 + lane] =
                Mlds[(rbase + ii) * 68 + lane] * scale;
    }
}

extern "C" void kernel_launch(void* const* d_in, const int* in_sizes, int n_in,
                              void* d_out, int out_size, void* d_ws, size_t ws_size,
                              hipStream_t stream) {
    const float* x = (const float*)d_in[0];   // [16,1,2048,64] fp32
    float* out = (float*)d_out;               // [16,4096] fp32

    const size_t need = (size_t)NCHUNK * 16 * 4096 * sizeof(float);  // 4 MB
    if (ws_size >= need) {
        // no-atomic path: partial max blocks in ws, reduced in jacobi prologue
        float* wsp = (float*)d_ws;
        hipLaunchKernelGGL(max_outer_part, dim3(NCHUNK, 16), dim3(256), 0, stream, x, wsp);
        hipLaunchKernelGGL(jacobi_sqrt, dim3(16), dim3(128), 0, stream,
                           (const void*)wsp, out, NCHUNK, 0);
    } else {
        // fallback: atomic max into mapped uints
        unsigned* wsu = (unsigned*)d_ws;
        hipLaunchKernelGGL(init_ws, dim3(256), dim3(256), 0, stream, wsu);
        hipLaunchKernelGGL(max_outer_atomic, dim3(NCHUNK, 16), dim3(256), 0, stream, x, wsu);
        hipLaunchKernelGGL(jacobi_sqrt, dim3(16), dim3(128), 0, stream,
                           (const void*)wsu, out, 1, 1);
    }
}

// Round 5
// 278.490 us; speedup vs baseline: 1.0322x; 1.0322x over previous
//
#include <hip/hip_runtime.h>
#include <math.h>

#define NSWEEP_FULL 6   // full sweeps (intra+cross); followed by one final intra phase
#define NCHUNK 16       // n-chunks in max_outer (2048/16 = 128 rows per block)

typedef float v2f __attribute__((ext_vector_type(2)));
typedef unsigned u2v __attribute__((ext_vector_type(2)));

__device__ __forceinline__ float dot4f(const float4 a, const float4 b) {
    return a.x * b.x + a.y * b.y + a.z * b.z + a.w * b.w;
}
// monotone float<->uint map so unsigned atomicMax == float max (handles negatives)
__device__ __forceinline__ unsigned mapf(float v) {
    unsigned u = __float_as_uint(v);
    return (u & 0x80000000u) ? ~u : (u | 0x80000000u);
}
__device__ __forceinline__ float unmapf(unsigned u) {
    return __uint_as_float((u & 0x80000000u) ? (u ^ 0x80000000u) : ~u);
}

// Cross-half (lane ^ 32) sum (shfl fallback is the measured-equal path).
__device__ __forceinline__ float xor32_sum(float part) {
    return part + __shfl_xor(part, 32);
}

// ws[0..65535] <- map(-inf)   (atomic-fallback path only)
__global__ __launch_bounds__(256) void init_ws(unsigned* __restrict__ wsu) {
    wsu[blockIdx.x * 256 + threadIdx.x] = 0x007FFFFFu;  // map of 0xFF800000 (-inf)
}

// Shared compute core for both max_outer variants: per-block 4x4-tile max.
// Products packed (v_pk_mul_f32); max stays scalar (no pk fp32 max on CDNA).
__device__ __forceinline__ void max_outer_core(const float* __restrict__ x,
                                               float m[4][4], float* xs,
                                               int b, int n0, int t, int ti, int tj) {
    v2f m2[4][2];
#pragma unroll
    for (int a = 0; a < 4; ++a)
#pragma unroll
        for (int c = 0; c < 2; ++c) m2[a][c] = (v2f){-3.402823466e38f, -3.402823466e38f};

    const int row = t >> 3, col8 = t & 7;     // staging map: 32 rows x 8 float-octs
    for (int sub = 0; sub < (2048 / NCHUNK) / 32; ++sub) {
        const float4* src4 =
            (const float4*)(x + (size_t)(b * 2048 + n0 + sub * 32 + row) * 64) + col8 * 2;
        float4* dst4 = (float4*)(xs + row * 64) + col8 * 2;
        dst4[0] = src4[0];
        dst4[1] = src4[1];
        __syncthreads();
#pragma unroll 8
        for (int rr = 0; rr < 32; ++rr) {
            const float4 av = ((const float4*)(xs + rr * 64))[ti];  // broadcast read
            const float4 bv = ((const float4*)(xs + rr * 64))[tj];  // stride-1 read
            const v2f b01 = {bv.x, bv.y}, b23 = {bv.z, bv.w};
            const float aa[4] = {av.x, av.y, av.z, av.w};
#pragma unroll
            for (int a = 0; a < 4; ++a) {
                const v2f av2 = {aa[a], aa[a]};
                const v2f p01 = av2 * b01;   // v_pk_mul_f32
                const v2f p23 = av2 * b23;
                m2[a][0].x = fmaxf(m2[a][0].x, p01.x);
                m2[a][0].y = fmaxf(m2[a][0].y, p01.y);
                m2[a][1].x = fmaxf(m2[a][1].x, p23.x);
                m2[a][1].y = fmaxf(m2[a][1].y, p23.y);
            }
        }
        __syncthreads();
    }
#pragma unroll
    for (int a = 0; a < 4; ++a) {
        m[a][0] = m2[a][0].x; m[a][1] = m2[a][0].y;
        m[a][2] = m2[a][1].x; m[a][3] = m2[a][1].y;
    }
}

// No-atomic path: each (chunk,b) block writes its private 64x64 max partial.
// ws layout: wsp[(b*NCHUNK + chunk)*4096 + i*64 + j]. grid = (NCHUNK, 16).
__global__ __launch_bounds__(256) void max_outer_part(const float* __restrict__ x,
                                                      float* __restrict__ wsp) {
    __shared__ __align__(16) float xs[32 * 64];
    const int b = blockIdx.y;
    const int t = threadIdx.x;
    const int ti = t >> 4, tj = t & 15;
    float m[4][4];
    max_outer_core(x, m, xs, b, blockIdx.x * (2048 / NCHUNK), t, ti, tj);
    float* cell = wsp + (((size_t)b * NCHUNK + blockIdx.x) << 12);
#pragma unroll
    for (int a = 0; a < 4; ++a) {
        float4 v;
        v.x = m[a][0]; v.y = m[a][1]; v.z = m[a][2]; v.w = m[a][3];
        *(float4*)(cell + (ti * 4 + a) * 64 + tj * 4) = v;
    }
}

// Atomic fallback (used only if ws too small): upper triangle only.
__global__ __launch_bounds__(256) void max_outer_atomic(const float* __restrict__ x,
                                                        unsigned* __restrict__ wsu) {
    __shared__ __align__(16) float xs[32 * 64];
    const int b = blockIdx.y;
    const int t = threadIdx.x;
    const int ti = t >> 4, tj = t & 15;
    float m[4][4];
    max_outer_core(x, m, xs, b, blockIdx.x * (2048 / NCHUNK), t, ti, tj);
    unsigned* cell = wsu + b * 4096;
#pragma unroll
    for (int a = 0; a < 4; ++a)
#pragma unroll
        for (int c = 0; c < 4; ++c) {
            const int gi = ti * 4 + a, gj = tj * 4 + c;
            if (gj >= gi) atomicMax(cell + gi * 64 + gj, mapf(m[a][c]));
        }
}

// Packed 32-dot: 16 v_pk_fma_f32. Accumulation order is the reference order.
__device__ __forceinline__ float dot32v(const v2f* w, const v2f* p) {
    v2f a0 = {0.f, 0.f}, a1 = a0, a2 = a0, a3 = a0;
#pragma unroll
    for (int i = 0; i < 16; i += 4) {
        a0 = __builtin_elementwise_fma(w[i + 0], p[i + 0], a0);
        a1 = __builtin_elementwise_fma(w[i + 1], p[i + 1], a1);
        a2 = __builtin_elementwise_fma(w[i + 2], p[i + 2], a2);
        a3 = __builtin_elementwise_fma(w[i + 3], p[i + 3], a3);
    }
    const v2f s = (a0 + a1) + (a2 + a3);
    return s.x + s.y;
}

// TWO independent packed 32-dots, manually interleaved for ILP. Per-dot
// accumulator pattern identical to dot32v -> bit-identical results.
__device__ __forceinline__ void dot32v2(const v2f* wA, const v2f* pA,
                                        const v2f* wB, const v2f* pB,
                                        float& rA, float& rB) {
    v2f a0 = {0.f, 0.f}, a1 = a0, a2 = a0, a3 = a0;
    v2f b0 = a0, b1 = a0, b2 = a0, b3 = a0;
#pragma unroll
    for (int i = 0; i < 16; i += 4) {
        a0 = __builtin_elementwise_fma(wA[i + 0], pA[i + 0], a0);
        b0 = __builtin_elementwise_fma(wB[i + 0], pB[i + 0], b0);
        a1 = __builtin_elementwise_fma(wA[i + 1], pA[i + 1], a1);
        b1 = __builtin_elementwise_fma(wB[i + 1], pB[i + 1], b1);
        a2 = __builtin_elementwise_fma(wA[i + 2], pA[i + 2], a2);
        b2 = __builtin_elementwise_fma(wB[i + 2], pB[i + 2], b2);
        a3 = __builtin_elementwise_fma(wA[i + 3], pA[i + 3], a3);
        b3 = __builtin_elementwise_fma(wB[i + 3], pB[i + 3], b3);
    }
    const v2f sA = (a0 + a1) + (a2 + a3);
    const v2f sB = (b0 + b1) + (b2 + b3);
    rA = sA.x + sA.y;
    rB = sB.x + sB.y;
}

// Rotation + packed update (reference single-pair form).
__device__ __forceinline__ void rot_update(float g, float np, bool lo, float& n,
                                           v2f* w, const v2f* p) {
    float cc = 1.f, ss2 = 0.f, dn = 0.f;
    if (fabsf(g) > 1e-25f) {
        const float a2 = lo ? n : np;   // norm^2 of lower-indexed column
        const float b2 = lo ? np : n;
        const float tau = (b2 - a2) * 0.5f * __builtin_amdgcn_rcpf(g);
        const float t = (tau >= 0.f ? 1.f : -1.f) *
                        __builtin_amdgcn_rcpf(fabsf(tau) + sqrtf(fmaf(tau, tau, 1.f)));
        cc = __builtin_amdgcn_rsqf(fmaf(t, t, 1.f));
        const float s = t * cc;
        const float sg = lo ? -1.f : 1.f;
        ss2 = sg * s;          // lo: w' = c w - s p ; hi: w' = c w + s p
        dn = sg * (t * g);     // a2' = a2 - t g ; b2' = b2 + t g
    }
    n += dn;
    const v2f ccv = {cc, cc}, ssv = {ss2, ss2};
#pragma unroll
    for (int i = 0; i < 16; ++i)
        w[i] = __builtin_elementwise_fma(ssv, p[i], w[i] * ccv);
}

// TWO independent rotation-coefficient chains, interleaved straight-line.
// Unconditional compute + final selects == the guarded form (NaN paths are
// selected out), and when |g|>1e-25 the op sequence matches rot_update
// exactly -> bit-identical coefficients.
__device__ __forceinline__ void rot_coeffs2(float gA, float npA, bool loA, float nA,
                                            float gB, float npB, bool loB, float nB,
                                            float& ccA, float& ssA, float& dnA,
                                            float& ccB, float& ssB, float& dnB) {
    const float a2A = loA ? nA : npA, b2A = loA ? npA : nA;
    const float a2B = loB ? nB : npB, b2B = loB ? npB : nB;
    const float tauA = (b2A - a2A) * 0.5f * __builtin_amdgcn_rcpf(gA);
    const float tauB = (b2B - a2B) * 0.5f * __builtin_amdgcn_rcpf(gB);
    const float rtA = sqrtf(fmaf(tauA, tauA, 1.f));
    const float rtB = sqrtf(fmaf(tauB, tauB, 1.f));
    const float tA = (tauA >= 0.f ? 1.f : -1.f) * __builtin_amdgcn_rcpf(fabsf(tauA) + rtA);
    const float tB = (tauB >= 0.f ? 1.f : -1.f) * __builtin_amdgcn_rcpf(fabsf(tauB) + rtB);
    const float cA = __builtin_amdgcn_rsqf(fmaf(tA, tA, 1.f));
    const float cB = __builtin_amdgcn_rsqf(fmaf(tB, tB, 1.f));
    const float sgA = loA ? -1.f : 1.f;
    const float sgB = loB ? -1.f : 1.f;
    const bool okA = fabsf(gA) > 1e-25f;
    const bool okB = fabsf(gB) > 1e-25f;
    ccA = okA ? cA : 1.f;
    ssA = okA ? sgA * (tA * cA) : 0.f;
    dnA = okA ? sgA * (tA * gA) : 0.f;
    ccB = okB ? cB : 1.f;
    ssB = okB ? sgB * (tB * cB) : 0.f;
    dnB = okB ? sgB * (tB * gB) : 0.f;
}

// TWO independent column updates, interleaved (per-element math identical).
__device__ __forceinline__ void update2(float ccA, float ssA, v2f* wA, const v2f* pA,
                                        float ccB, float ssB, v2f* wB, const v2f* pB) {
    const v2f cAv = {ccA, ccA}, sAv = {ssA, ssA};
    const v2f cBv = {ccB, ccB}, sBv = {ssB, ssB};
#pragma unroll
    for (int i = 0; i < 16; ++i) {
        wA[i] = __builtin_elementwise_fma(sAv, pA[i], wA[i] * cAv);
        wB[i] = __builtin_elementwise_fma(sBv, pB[i], wB[i] * cBv);
    }
}

// Column exchange helpers (xbuf row = 36 floats: 32 data + norm + pad).
__device__ __forceinline__ void store_col(float* myx, const v2f* w, float n) {
#pragma unroll
    for (int c = 0; c < 8; ++c) {
        float4 v;
        v.x = w[2 * c].x; v.y = w[2 * c].y;
        v.z = w[2 * c + 1].x; v.w = w[2 * c + 1].y;
        ((float4*)myx)[c] = v;
    }
    myx[32] = n;
}
__device__ __forceinline__ void load_col(const float* ox, v2f* p, float& np) {
#pragma unroll
    for (int c = 0; c < 8; ++c) {
        const float4 v = ((const float4*)ox)[c];
        p[2 * c] = (v2f){v.x, v.y};
        p[2 * c + 1] = (v2f){v.z, v.w};
    }
    np = ox[32];
}

// One-sided Jacobi, 2 waves per batch, TWO ROUNDS PER EXCHANGE (lookahead),
// with the two independent round-m computations (my pair + replicated
// partner pair) MANUALLY INTERLEAVED (dot32v2 / rot_coeffs2 / update2) and
// __launch_bounds__(128,1) to unlock the VGPR budget (R4 showed the
// compiler serialized the chains at the 128-VGPR occupancy tier).
// Replicated rotations are bit-identical to their owners' -> 409-round
// trajectory unchanged. Exchanges 409 -> 208, barriers 192 -> 96.
// grid = 16, block = 128.
__global__ __launch_bounds__(128, 1) void jacobi_sqrt(const void* __restrict__ wsv,
                                                      float* __restrict__ out,
                                                      int nchunk, int mapped) {
    __shared__ __align__(16) float Mlds[64 * 68];      // original M rows (stride 68)
    __shared__ __align__(16) float Ulds[64 * 68];      // U rows
    __shared__ __align__(16) float gl[64];             // signed sqrt eigenvalues
    __shared__ __align__(16) float xbuf[2][2][64][36]; // [buf][wave][lane][32w+n+pad]
    __shared__ float gred[2][2][64];                   // epilogue reductions
    const int b = blockIdx.x;
    const int tid = threadIdx.x;
    const int wave = tid >> 6;
    const int lane = tid & 63;
    const int col = wave * 32 + (lane & 31);  // column this lane serves
    const int r0 = (lane >> 5) * 32;          // first row of the half it holds

    v2f w[16], p1[16], p2[16], p3[16];
    // load my half-column + stash M rows in LDS for the epilogue
    if (mapped) {
        const unsigned* wsu = (const unsigned*)wsv;
#pragma unroll
        for (int i = 0; i < 16; ++i) {
            float vv[2];
#pragma unroll
            for (int h = 0; h < 2; ++h) {
                const int row = r0 + 2 * i + h;
                const int rr = row < col ? row : col;
                const int cc = row < col ? col : row;
                vv[h] = unmapf(wsu[b * 4096 + rr * 64 + cc]);
                Mlds[row * 68 + col] = vv[h];
            }
            w[i] = (v2f){vv[0], vv[1]};
        }
    } else {
        const float* wsp = (const float*)wsv + (((size_t)b * nchunk) << 12);
#pragma unroll
        for (int i = 0; i < 16; ++i) w[i] = (v2f){-3.402823466e38f, -3.402823466e38f};
#pragma unroll 1
        for (int ch = 0; ch < nchunk; ++ch) {
            const float* base = wsp + ((size_t)ch << 12) + (size_t)r0 * 64 + col;
#pragma unroll
            for (int i = 0; i < 16; ++i) {
                w[i].x = fmaxf(w[i].x, base[(2 * i) * 64]);
                w[i].y = fmaxf(w[i].y, base[(2 * i + 1) * 64]);
            }
        }
#pragma unroll
        for (int i = 0; i < 16; ++i) {
            Mlds[(r0 + 2 * i) * 68 + col] = w[i].x;
            Mlds[(r0 + 2 * i + 1) * 68 + col] = w[i].y;
        }
    }
    // initial column norm^2 (maintained analytically through the rotations)
    float n;
    {
        const float part = dot32v(w, w);
        n = xor32_sum(part);
    }

#pragma unroll 1
    for (int sweep = 0; sweep < NSWEEP_FULL + 1; ++sweep) {
        // ---- intra-wave: 15 fused double-rounds + 1 single, no barriers ----
#pragma unroll 1
        for (int m = 1; m < 31; m += 2) {
            const int m2 = m + 1, m3 = m ^ m2;
            store_col(&xbuf[0][wave][lane][0], w, n);
            asm volatile("" ::: "memory");
            float np1, np2, np3;
            load_col(&xbuf[0][wave][lane ^ m][0], p1, np1);
            load_col(&xbuf[0][wave][lane ^ m2][0], p2, np2);
            load_col(&xbuf[0][wave][lane ^ m3][0], p3, np3);
            const int c5 = lane & 31;
            // round m: my pair (col,col^m) and replicated pair (col^m2,col^m3)
            // computed INTERLEAVED (independent data -> ILP)
            float g1p, g2p;
            dot32v2(w, p1, p2, p3, g1p, g2p);
            const float g1 = xor32_sum(g1p);
            const float g2 = xor32_sum(g2p);
            float cc1, ss1, dn1, cc2, ss2, dn2;
            rot_coeffs2(g1, np1, c5 < (c5 ^ m), n,
                        g2, np3, (c5 ^ m2) < (c5 ^ m3), np2,
                        cc1, ss1, dn1, cc2, ss2, dn2);
            n += dn1;
            np2 += dn2;
            update2(cc1, ss1, w, p1, cc2, ss2, p2, p3);
            // round m2: my pair (col, col^m2) against locally-updated p2
            const float g3 = xor32_sum(dot32v(w, p2));
            rot_update(g3, np2, c5 < (c5 ^ m2), n, w, p2);
        }
        {   // leftover single round m=31
            store_col(&xbuf[0][wave][lane][0], w, n);
            asm volatile("" ::: "memory");
            float np1;
            load_col(&xbuf[0][wave][lane ^ 31][0], p1, np1);
            const float g = xor32_sum(dot32v(w, p1));
            rot_update(g, np1, (lane & 31) < ((lane & 31) ^ 31), n, w, p1);
        }
        if (sweep == NSWEEP_FULL) break;  // final phase is intra-only
        // ---- cross-wave: 16 fused double-rounds, ONE barrier each ----
#pragma unroll 1
        for (int m = 32; m < 64; m += 2) {
            const int m2 = m + 1;              // m ^ m2 == 1 (replica partner intra)
            const int buf = (m >> 1) & 1;
            store_col(&xbuf[buf][wave][lane][0], w, n);
            __syncthreads();
            float np1, np2, np3;
            load_col(&xbuf[buf][wave ^ 1][lane ^ (m & 31)][0], p1, np1);
            load_col(&xbuf[buf][wave ^ 1][lane ^ (m2 & 31)][0], p2, np2);
            load_col(&xbuf[buf][wave][lane ^ 1][0], p3, np3);
            // round m: my pair (lower col in wave 0) and replicated pair
            // (col^m2 [other wave], col^1 [my wave]; lower col in wave^1)
            float g1p, g2p;
            dot32v2(w, p1, p2, p3, g1p, g2p);
            const float g1 = xor32_sum(g1p);
            const float g2 = xor32_sum(g2p);
            float cc1, ss1, dn1, cc2, ss2, dn2;
            rot_coeffs2(g1, np1, wave == 0, n,
                        g2, np3, wave != 0, np2,
                        cc1, ss1, dn1, cc2, ss2, dn2);
            n += dn1;
            np2 += dn2;
            update2(cc1, ss1, w, p1, cc2, ss2, p2, p3);
            // round m2: my pair (col, col^m2)
            const float g3 = xor32_sum(dot32v(w, p2));
            rot_update(g3, np2, wave == 0, n, w, p2);
        }
    }

    // ---- exact norm -> u (intra-wave) ----
    {
        const float part = dot32v(w, w);
        const float nrm = xor32_sum(part);
        const float inv = rsqrtf(fmaxf(nrm, 1e-30f));
        const v2f iv = {inv, inv};
#pragma unroll
        for (int i = 0; i < 16; ++i) w[i] = w[i] * iv;
    }
    // U rows into LDS (conflict-free: distinct cols mod 32 per half)
#pragma unroll
    for (int i = 0; i < 16; ++i) {
        Ulds[(r0 + 2 * i) * 68 + col] = w[i].x;
        Ulds[(r0 + 2 * i + 1) * 68 + col] = w[i].y;
    }
    __syncthreads();

    // ---- switch to row-split layout: lane = column, wave owns rows ----
    const int rbase = wave * 32;
    const int obase = 32 - rbase;
    float w2[32], p2r[32];
#pragma unroll
    for (int i = 0; i < 32; ++i) w2[i] = Ulds[(rbase + i) * 68 + lane];
#pragma unroll
    for (int i = 0; i < 32; ++i) p2r[i] = Ulds[(obase + i) * 68 + lane];

    // ---- signed eigenvalue: rho = u^T M u (i split by ownership, j full) ----
    {
        float rho = 0.f;
#pragma unroll 1
        for (int ii = 0; ii < 32; ++ii) {
            const int i = rbase + ii;
            const float4* mrw = (const float4*)(Mlds + i * 68) + (rbase >> 2);  // rows of w2
            const float4* mrp = (const float4*)(Mlds + i * 68) + (obase >> 2);  // rows of p2r
            float z0 = 0, z1 = 0, z2 = 0, z3 = 0;
#pragma unroll
            for (int c = 0; c < 8; c += 4) {
                float4 mv;
                mv = mrw[c + 0]; z0 += mv.x * w2[4 * c + 0]  + mv.y * w2[4 * c + 1]  + mv.z * w2[4 * c + 2]  + mv.w * w2[4 * c + 3];
                mv = mrw[c + 1]; z1 += mv.x * w2[4 * c + 4]  + mv.y * w2[4 * c + 5]  + mv.z * w2[4 * c + 6]  + mv.w * w2[4 * c + 7];
                mv = mrw[c + 2]; z2 += mv.x * w2[4 * c + 8]  + mv.y * w2[4 * c + 9]  + mv.z * w2[4 * c + 10] + mv.w * w2[4 * c + 11];
                mv = mrw[c + 3]; z3 += mv.x * w2[4 * c + 12] + mv.y * w2[4 * c + 13] + mv.z * w2[4 * c + 14] + mv.w * w2[4 * c + 15];
                mv = mrp[c + 0]; z0 += mv.x * p2r[4 * c + 0]  + mv.y * p2r[4 * c + 1]  + mv.z * p2r[4 * c + 2]  + mv.w * p2r[4 * c + 3];
                mv = mrp[c + 1]; z1 += mv.x * p2r[4 * c + 4]  + mv.y * p2r[4 * c + 5]  + mv.z * p2r[4 * c + 6]  + mv.w * p2r[4 * c + 7];
                mv = mrp[c + 2]; z2 += mv.x * p2r[4 * c + 8]  + mv.y * p2r[4 * c + 9]  + mv.z * p2r[4 * c + 10] + mv.w * p2r[4 * c + 11];
                mv = mrp[c + 3]; z3 += mv.x * p2r[4 * c + 12] + mv.y * p2r[4 * c + 13] + mv.z * p2r[4 * c + 14] + mv.w * p2r[4 * c + 15];
            }
            rho = fmaf(w2[ii], (z0 + z1) + (z2 + z3), rho);
        }
        gred[1][wave][lane] = rho;
        __syncthreads();
        const float rs = gred[1][0][lane] + gred[1][1][lane];
        gl[lane] = (rs >= 0.f) ? sqrtf(rs) : -sqrtf(-rs);  // both waves write same value
    }
    __syncthreads();

    // ---- F[i][lane] = sum_k g_k U[i][k] U[lane][k], i over my rows ----
    {
        float4 rr[16];  // row `lane` of U scaled by g
#pragma unroll
        for (int c = 0; c < 16; ++c) {
            const float4 uv = ((const float4*)(Ulds + lane * 68))[c];
            const float4 gv = ((const float4*)gl)[c];  // broadcast
            rr[c].x = uv.x * gv.x; rr[c].y = uv.y * gv.y;
            rr[c].z = uv.z * gv.z; rr[c].w = uv.w * gv.w;
        }
        float sq = 0.f;
#pragma unroll 1
        for (int ii = 0; ii < 32; ++ii) {
            const int i = rbase + ii;
            const float4* ur = (const float4*)(Ulds + i * 68);  // broadcast
            float f0 = 0, f1 = 0, f2 = 0, f3 = 0;
#pragma unroll
            for (int c = 0; c < 16; c += 4) {
                f0 += dot4f(ur[c + 0], rr[c + 0]);
                f1 += dot4f(ur[c + 1], rr[c + 1]);
                f2 += dot4f(ur[c + 2], rr[c + 2]);
                f3 += dot4f(ur[c + 3], rr[c + 3]);
            }
            const float fv = (f0 + f1) + (f2 + f3);
            sq = fmaf(fv, fv, sq);
            Mlds[i * 68 + lane] = fv;  // M is dead; reuse as F staging
        }
#pragma unroll
        for (int d = 1; d < 64; d <<= 1) sq += __shfl_xor(sq, d);
        gred[0][wave][lane] = sq;
        __syncthreads();
        const float tot = gred[0][0][lane] + gred[0][1][lane];
        const float scale = 1.f / fmaxf(sqrtf(tot), 1e-12f);
#pragma unroll 1
        for (int ii = 0; ii < 32; ++ii)
            out[(size_t)b * 4096 + (rbase + ii) * 64 + lane] =
                Mlds[(rbase + ii) * 68 + lane] * scale;
    }
}

extern "C" void kernel_launch(void* const* d_in, const int* in_sizes, int n_in,
                              void* d_out, int out_size, void* d_ws, size_t ws_size,
                              hipStream_t stream) {
    const float* x = (const float*)d_in[0];   // [16,1,2048,64] fp32
    float* out = (float*)d_out;               // [16,4096] fp32

    const size_t need = (size_t)NCHUNK * 16 * 4096 * sizeof(float);  // 4 MB
    if (ws_size >= need) {
        // no-atomic path: partial max blocks in ws, reduced in jacobi prologue
        float* wsp = (float*)d_ws;
        hipLaunchKernelGGL(max_outer_part, dim3(NCHUNK, 16), dim3(256), 0, stream, x, wsp);
        hipLaunchKernelGGL(jacobi_sqrt, dim3(16), dim3(128), 0, stream,
                           (const void*)wsp, out, NCHUNK, 0);
    } else {
        // fallback: atomic max into mapped uints
        unsigned* wsu = (unsigned*)d_ws;
        hipLaunchKernelGGL(init_ws, dim3(256), dim3(256), 0, stream, wsu);
        hipLaunchKernelGGL(max_outer_atomic, dim3(NCHUNK, 16), dim3(256), 0, stream, x, wsu);
        hipLaunchKernelGGL(jacobi_sqrt, dim3(16), dim3(128), 0, stream,
                           (const void*)wsu, out, 1, 1);
    }
}